// Round 9
// baseline (164.197 us; speedup 1.0000x reference)
//
#include <hip/hip_runtime.h>

#define N_NODES 50000
#define F_IN 128
#define OUT_F 128
#define JF 256
#define EDGES 600000
#define BN_EPS 1e-5f
#define MAXDEG 48
#define NPART 8
#define PART_ROWS 6250   // N_NODES / NPART
#define CHUNK_E 2048
#define NCHUNK 586       // 586*2048 = 1200128 >= 2E

#define SCAT_B (NPART * NCHUNK)   // 4688
#define CONVX_B 6250     // N*F_IN/4/256
#define CONVW_B 32       // 128*256/4/256
#define BUILD_B (SCAT_B + CONVX_B + CONVW_B)
#define FUSE_B 3125      // N/16 exactly
#define NCOPY 16         // stats replication

typedef __attribute__((ext_vector_type(8))) short short8;
typedef __attribute__((ext_vector_type(4))) float floatx4;
typedef __attribute__((ext_vector_type(4))) unsigned short ushortx4;

static __device__ __forceinline__ unsigned short f2bf(float f) {
    unsigned int x = __float_as_uint(f);
    unsigned int r = (x + 0x7fffu + ((x >> 16) & 1u)) >> 16;
    return (unsigned short)r;
}
static __device__ __forceinline__ float bflo(unsigned int p) { return __uint_as_float(p << 16); }
static __device__ __forceinline__ float bfhi(unsigned int p) { return __uint_as_float(p & 0xffff0000u); }

// ---------------------------------------------------------------------------
// Fused build: XCD-partitioned row-major ELL scatter + x/W -> bf16 converts.
// ---------------------------------------------------------------------------
__global__ __launch_bounds__(256) void build_kernel(
    const int* __restrict__ rows0, const int* __restrict__ cols0, const float* __restrict__ vals0,
    const int* __restrict__ rows1, const int* __restrict__ cols1, const float* __restrict__ vals1,
    int* __restrict__ cnt0, int* __restrict__ cnt1,
    unsigned int* __restrict__ pe0, unsigned int* __restrict__ pe1,
    const floatx4* __restrict__ x4, ushortx4* __restrict__ xb4,
    const floatx4* __restrict__ W4, ushortx4* __restrict__ Wb4)
{
    int bid = blockIdx.x;
    int tid = threadIdx.x;
    if (bid < SCAT_B) {
        unsigned part = (unsigned)(bid & (NPART - 1));
        int c0 = (bid >> 3) * CHUNK_E;

        bool pure0 = (c0 + CHUNK_E <= EDGES);
        bool pure1 = (c0 >= EDGES) && (c0 + CHUNK_E <= 2 * EDGES);
        if (pure0 || pure1) {
            const int*   rows = pure1 ? rows1 : rows0;
            const int*   cols = pure1 ? cols1 : cols0;
            const float* vals = pure1 ? vals1 : vals0;
            int*          cnt = pure1 ? cnt1 : cnt0;
            unsigned int*  pe = pure1 ? pe1 : pe0;
            int eb = pure1 ? c0 - EDGES : c0;
            #pragma unroll
            for (int g = 0; g < 2; ++g) {
                int e = eb + g * 1024 + tid * 4;
                int4 rv = *(const int4*)(rows + e);
                int rr[4] = {rv.x, rv.y, rv.z, rv.w};
                #pragma unroll
                for (int j = 0; j < 4; ++j) {
                    int r = rr[j];
                    if ((unsigned)r / (unsigned)PART_ROWS == part) {
                        int ee = e + j;
                        int c = cols[ee];
                        float v = vals[ee];
                        int p = atomicAdd(&cnt[r], 1);
                        if (p < MAXDEG)
                            pe[(size_t)r * MAXDEG + p] = ((unsigned int)c << 16) | f2bf(v);
                    }
                }
            }
        } else {
            for (int i = 0; i < CHUNK_E / 256; ++i) {
                int e = c0 + i * 256 + tid;
                if (e < 2 * EDGES) {
                    bool s1 = e >= EDGES;
                    int ee = s1 ? e - EDGES : e;
                    int r = s1 ? rows1[ee] : rows0[ee];
                    if ((unsigned)r / (unsigned)PART_ROWS == part) {
                        int c = s1 ? cols1[ee] : cols0[ee];
                        float v = s1 ? vals1[ee] : vals0[ee];
                        int* cnt = s1 ? cnt1 : cnt0;
                        unsigned int* pe = s1 ? pe1 : pe0;
                        int p = atomicAdd(&cnt[r], 1);
                        if (p < MAXDEG)
                            pe[(size_t)r * MAXDEG + p] = ((unsigned int)c << 16) | f2bf(v);
                    }
                }
            }
        }
    } else if (bid < SCAT_B + CONVX_B) {
        int i = (bid - SCAT_B) * 256 + tid;
        floatx4 v = __builtin_nontemporal_load(&x4[i]);
        ushortx4 o;
        o.x = f2bf(v.x); o.y = f2bf(v.y); o.z = f2bf(v.z); o.w = f2bf(v.w);
        __builtin_nontemporal_store(o, &xb4[i]);
    } else {
        int i = (bid - SCAT_B - CONVX_B) * 256 + tid;
        floatx4 v = W4[i];
        ushortx4 o;
        o.x = f2bf(v.x); o.y = f2bf(v.y); o.z = f2bf(v.z); o.w = f2bf(v.w);
        Wb4[i] = o;
    }
}

// ---------------------------------------------------------------------------
// Branchless ELL record accumulate: inactive slots gather xb row 0 (L1-hot)
// with weight forced to 0 -> no exec-mask regions, full MLP.
// ---------------------------------------------------------------------------
static __device__ __forceinline__ void rec2(
    unsigned int q, bool on, int lane,
    const unsigned int* __restrict__ xb32, float& A0, float& A1)
{
    unsigned int idx = on ? (q >> 16) : 0u;
    float vv = on ? __uint_as_float(q << 16) : 0.0f;
    unsigned int xv = xb32[idx * 64 + lane];
    A0 += vv * bflo(xv);
    A1 += vv * bfhi(xv);
}

// ---------------------------------------------------------------------------
// Fused gather + MFMA GEMM + BN stats. 16 rows/block, 4 waves.
// Phase 0: cooperative coalesced staging of all ELL records + cnts into LDS.
// Phase 1: wave w gathers rows w*4..w*4+3; records come from LDS (short
//          chain head), 48 branchless gathers per row issued back-to-back.
// Phase 2: 16x128 tile; wave w does cols w*32..w*32+31 via mfma 16x16x32.
// ---------------------------------------------------------------------------
__global__ __launch_bounds__(256, 4) void gather_gemm(
    const unsigned int* __restrict__ xb32,
    const int* __restrict__ cnt0, const unsigned int* __restrict__ pe0,
    const int* __restrict__ cnt1, const unsigned int* __restrict__ pe1,
    const ushort* __restrict__ Wb, const float* __restrict__ bias,
    float* __restrict__ y, float* __restrict__ stats)
{
    __shared__ unsigned int hsu[16 * 128];   // 8 KB: 16 rows x 256 bf16, swizzled
    __shared__ uint4 recs[2][16][6];         // 3 KB: staged ELL records
    __shared__ int   lcnt[2][16];
    __shared__ float lstat[256];

    int tid = threadIdx.x;
    int lane = tid & 63;
    int w = tid >> 6;
    int wu = __builtin_amdgcn_readfirstlane(w);
    int row0 = blockIdx.x * 16;

    lstat[tid] = 0.f;

    // ---- phase 0: stage records + counts into LDS (coalesced) ----
    {
        int row = tid >> 4, j = tid & 15;
        if (j < 12) {
            int side = j >= 6;
            int g = j - side * 6;
            const unsigned int* pe = side ? pe1 : pe0;
            recs[side][row][g] = *(const uint4*)(pe + (size_t)(row0 + row) * MAXDEG + g * 4);
        } else if (j == 12) {
            int d = cnt0[row0 + row]; lcnt[0][row] = d > MAXDEG ? MAXDEG : d;
        } else if (j == 13) {
            int d = cnt1[row0 + row]; lcnt[1][row] = d > MAXDEG ? MAXDEG : d;
        }
    }
    __syncthreads();

    // ---- phase 1: gather 4 rows per wave ----
    for (int rr = 0; rr < 4; ++rr) {
        int lr = wu * 4 + rr;
        int r = row0 + lr;
        int d0 = lcnt[0][lr];
        int d1 = lcnt[1][lr];

        float aL0 = 0.f, aL1 = 0.f, aR0 = 0.f, aR1 = 0.f;

        #pragma unroll
        for (int g = 0; g < 6; ++g) {
            uint4 q = recs[0][lr][g];
            rec2(q.x, g * 4 + 0 < d0, lane, xb32, aL0, aL1);
            rec2(q.y, g * 4 + 1 < d0, lane, xb32, aL0, aL1);
            rec2(q.z, g * 4 + 2 < d0, lane, xb32, aL0, aL1);
            rec2(q.w, g * 4 + 3 < d0, lane, xb32, aL0, aL1);
        }
        #pragma unroll
        for (int g = 0; g < 6; ++g) {
            uint4 q = recs[1][lr][g];
            rec2(q.x, g * 4 + 0 < d1, lane, xb32, aR0, aR1);
            rec2(q.y, g * 4 + 1 < d1, lane, xb32, aR0, aR1);
            rec2(q.z, g * 4 + 2 < d1, lane, xb32, aR0, aR1);
            rec2(q.w, g * 4 + 3 < d1, lane, xb32, aR0, aR1);
        }
        // rare tails (deg > 24): straight from global
        if (d0 > 24)
            for (int p = 24; p < d0; ++p)
                rec2(pe0[(size_t)r * MAXDEG + p], true, lane, xb32, aL0, aL1);
        if (d1 > 24)
            for (int p = 24; p < d1; ++p)
                rec2(pe1[(size_t)r * MAXDEG + p], true, lane, xb32, aR0, aR1);

        unsigned int sw = (unsigned int)((lr & 7) << 4);
        unsigned int offL = ((unsigned int)(lr * 512 + lane * 4)) ^ sw;
        unsigned int offR = ((unsigned int)(lr * 512 + 256 + lane * 4)) ^ sw;
        *(unsigned int*)((char*)hsu + offL) =
            (unsigned int)f2bf(aL0) | ((unsigned int)f2bf(aL1) << 16);
        *(unsigned int*)((char*)hsu + offR) =
            (unsigned int)f2bf(aR0) | ((unsigned int)f2bf(aR1) << 16);
    }
    __syncthreads();

    // ---- phase 2: 16x32 per wave, K=256 ----
    floatx4 acc[2];
    acc[0] = (floatx4){0.f, 0.f, 0.f, 0.f};
    acc[1] = (floatx4){0.f, 0.f, 0.f, 0.f};

    int colb = lane & 15;
    int kg = lane >> 4;
    unsigned int asw = (unsigned int)((colb & 7) << 4);
    const char* hbase = (const char*)hsu;
    const ushort* wp = Wb + (size_t)(w * 32 + colb) * JF + kg * 8;

    #pragma unroll
    for (int k0 = 0; k0 < 8; ++k0) {
        unsigned int aoff = ((unsigned int)(colb * 512 + k0 * 64 + kg * 16)) ^ asw;
        short8 a = *(const short8*)(hbase + aoff);
        #pragma unroll
        for (int c = 0; c < 2; ++c) {
            short8 b = *(const short8*)(wp + c * 16 * JF + k0 * 32);
            acc[c] = __builtin_amdgcn_mfma_f32_16x16x32_bf16(a, b, acc[c], 0, 0, 0);
        }
    }

    // ---- epilogue: bias, y write, stats ----
    int rq = kg * 4;
    #pragma unroll
    for (int c = 0; c < 2; ++c) {
        int col = w * 32 + c * 16 + colb;
        float bv = bias[col];
        float s = 0.f, s2 = 0.f;
        #pragma unroll
        for (int q = 0; q < 4; ++q) {
            float val = acc[c][q] + bv;
            y[(size_t)(row0 + rq + q) * OUT_F + col] = val;
            s += val; s2 += val * val;
        }
        atomicAdd(&lstat[col], s);
        atomicAdd(&lstat[128 + col], s2);
    }
    __syncthreads();
    float* sdst = stats + (size_t)(blockIdx.x & (NCOPY - 1)) * 256;
    atomicAdd(&sdst[tid], lstat[tid]);
}

// ---------------------------------------------------------------------------
// BN scale/shift prep: fold NCOPY stat replicas.
// ---------------------------------------------------------------------------
__global__ void bn_prep(const float* __restrict__ stats,
                        const float* __restrict__ gamma,
                        const float* __restrict__ beta,
                        float* __restrict__ ss)
{
    int o = threadIdx.x;
    if (o >= OUT_F) return;
    float s = 0.f, s2 = 0.f;
    #pragma unroll
    for (int c = 0; c < NCOPY; ++c) {
        s  += stats[c * 256 + o];
        s2 += stats[c * 256 + 128 + o];
    }
    float inv_n = 1.0f / (float)N_NODES;
    float mean = s * inv_n;
    float var  = s2 * inv_n - mean * mean;
    float sc = rsqrtf(var + BN_EPS) * gamma[o];
    ss[o] = sc;
    ss[OUT_F + o] = beta[o] - mean * sc;
}

// ---------------------------------------------------------------------------
// BN apply.
// ---------------------------------------------------------------------------
__global__ __launch_bounds__(256) void bn_apply(
    float* __restrict__ y, const float* __restrict__ ss)
{
    size_t i = (size_t)blockIdx.x * blockDim.x + threadIdx.x;
    size_t total = (size_t)N_NODES * OUT_F / 4;
    if (i >= total) return;

    int c4 = (int)(i & (OUT_F / 4 - 1));
    float4 v  = ((const float4*)y)[i];
    float4 sc = ((const float4*)ss)[c4];
    float4 sh = ((const float4*)(ss + OUT_F))[c4];
    v.x = v.x * sc.x + sh.x;
    v.y = v.y * sc.y + sh.y;
    v.z = v.z * sc.z + sh.z;
    v.w = v.w * sc.w + sh.w;
    ((float4*)y)[i] = v;
}

extern "C" void kernel_launch(void* const* d_in, const int* in_sizes, int n_in,
                              void* d_out, int out_size, void* d_ws, size_t ws_size,
                              hipStream_t stream)
{
    const float* x     = (const float*)d_in[0];
    const int*   rows0 = (const int*)  d_in[1];
    const int*   cols0 = (const int*)  d_in[2];
    const float* vals0 = (const float*)d_in[3];
    const int*   rows1 = (const int*)  d_in[4];
    const int*   cols1 = (const int*)  d_in[5];
    const float* vals1 = (const float*)d_in[6];
    const float* W     = (const float*)d_in[7];
    const float* b     = (const float*)d_in[8];
    const float* gamma = (const float*)d_in[9];
    const float* beta  = (const float*)d_in[10];

    float* y = (float*)d_out;

    // workspace layout
    ushort* xb = (ushort*)d_ws;                                  // N*128 bf16 (12.8 MB)
    ushort* Wb = xb + (size_t)N_NODES * F_IN;                    // 128*256 bf16 (64 KB)
    unsigned int* pe0 = (unsigned int*)(Wb + OUT_F * JF);        // N*MAXDEG (9.6 MB), row-major
    unsigned int* pe1 = pe0 + (size_t)N_NODES * MAXDEG;          // N*MAXDEG (9.6 MB)
    int* cnt0 = (int*)(pe1 + (size_t)N_NODES * MAXDEG);          // N   <- zero region
    int* cnt1 = cnt0 + N_NODES;                                  // N
    float* stats = (float*)(cnt1 + N_NODES);                     // NCOPY*256
    float* ss    = stats + NCOPY * 256;                          // 256

    // zero cnt0, cnt1, stats
    hipMemsetAsync(cnt0, 0, (2 * (size_t)N_NODES + NCOPY * 256) * sizeof(int), stream);

    // partitioned ELL build + bf16 conversions
    build_kernel<<<BUILD_B, 256, 0, stream>>>(
        rows0, cols0, vals0, rows1, cols1, vals1,
        cnt0, cnt1, pe0, pe1,
        (const floatx4*)x, (ushortx4*)xb, (const floatx4*)W, (ushortx4*)Wb);

    // fused gather + GEMM + stats
    gather_gemm<<<FUSE_B, 256, 0, stream>>>(
        (const unsigned int*)xb, cnt0, pe0, cnt1, pe1, Wb, b, y, stats);

    // BN
    bn_prep<<<1, 128, 0, stream>>>(stats, gamma, beta, ss);
    bn_apply<<<CONVX_B, 256, 0, stream>>>(y, ss);
}